// Round 8
// baseline (90.804 us; speedup 1.0000x reference)
//
#include <hip/hip_runtime.h>
#include <hip/hip_bf16.h>

#define NPIX 9216
#define MTILES (NPIX / 16)    // 576

typedef __attribute__((ext_vector_type(4))) float f32x4;
typedef __attribute__((ext_vector_type(8))) short bf16x8;
typedef __attribute__((ext_vector_type(2))) unsigned int u32x2;

__device__ __forceinline__ void gload_lds16(const void* g, void* l) {
  __builtin_amdgcn_global_load_lds(
      (const __attribute__((address_space(1))) unsigned int*)g,
      (__attribute__((address_space(3))) unsigned int*)l, 16, 0, 0);
}
__device__ __forceinline__ void gload_lds4(const void* g, void* l) {
  __builtin_amdgcn_global_load_lds(
      (const __attribute__((address_space(1))) unsigned int*)g,
      (__attribute__((address_space(3))) unsigned int*)l, 4, 0, 0);
}
#define LDS_OFF(p) ((unsigned)(unsigned long long)(const __attribute__((address_space(3))) char*)(const char*)(p))

// ---------------- Kernel 1: f,g,h projections (+fused spectral norm) --------
// Qp  : [NPIX][16] bf16  (qh[0..7], ql[0..7]) of (f * 0.25)  [hi/lo split]
// Kp  : [288 tiles][1KB], PLANE-SPLIT (no XOR): hi plane = 32 rows x 16B at
//        byte n*16; lo plane at byte 512 + n*16.  Rows at 16B stride ->
//        ds_read_b128 across 16 rows = consecutive bank groups, 2-way (free);
//        g-groups broadcast.  Writer/stager/reader all linear+additive.
// Vt2 : [288 tiles][4KB]: element (c, n=16t+4g+i) at ushort idx
//        tile*2048 + ((c*32 + g*8 + t*4 + i) ^ (((c>>1)&7)<<3))
//        (XOR of FULL index -> bijective; spreads lanes across bank groups).
// Block = 16 pixels x 80 rows; x-tile + all W staged in LDS.
__global__ __launch_bounds__(256) void fgh_kernel(
    const float* __restrict__ x,
    const float* __restrict__ Wf, const float* __restrict__ bfv,
    const float* __restrict__ Wg, const float* __restrict__ bgv,
    const float* __restrict__ Wh, const float* __restrict__ bhv,
    const float* __restrict__ uf, const float* __restrict__ ug,
    const float* __restrict__ uh,
    ushort* __restrict__ Qp, ushort* __restrict__ Kp, ushort* __restrict__ Vt2) {
  __shared__ float xs[64][16];   // [c][px]
  __shared__ float Ws[80][65];   // rows: f 0-7, g 8-15, h 16-79; +1 pad
  __shared__ float vsh[64];
  __shared__ float is_s[3];
  const int tid = threadIdx.x;

  // stage x tile and W matrices
  const int p0 = blockIdx.x * 16;
  #pragma unroll
  for (int e = tid; e < 1024; e += 256) {
    const int c = e >> 4, px = e & 15;
    xs[c][px] = x[c * NPIX + p0 + px];
  }
  for (int e = tid; e < 512; e += 256) Ws[e >> 6][e & 63]       = Wf[e];
  for (int e = tid; e < 512; e += 256) Ws[8 + (e >> 6)][e & 63]  = Wg[e];
  for (int e = tid; e < 4096; e += 256) Ws[16 + (e >> 6)][e & 63] = Wh[e];

  if (tid < 64) {  // one wave: spectral sigmas (redundant per block, small)
    const int t = tid;
    for (int widx = 0; widx < 3; ++widx) {
      const float* W = (widx == 0) ? Wf : (widx == 1) ? Wg : Wh;
      const float* u = (widx == 0) ? uf : (widx == 1) ? ug : uh;
      const int O = (widx == 2) ? 64 : 8;
      float v = 0.f;
      for (int o = 0; o < O; ++o) v += W[o * 64 + t] * u[o];
      float s = v * v;
      for (int off = 32; off; off >>= 1) s += __shfl_xor(s, off);
      vsh[t] = v / (sqrtf(s) + 1e-12f);   // wave-lockstep
      float wv = 0.f;
      if (t < O) { for (int c = 0; c < 64; ++c) wv += W[t * 64 + c] * vsh[c]; }
      float s2 = (t < O) ? wv * wv : 0.f;
      for (int off = 32; off; off >>= 1) s2 += __shfl_xor(s2, off);
      const float nw = sqrtf(s2);
      if (t == 0) is_s[widx] = (nw + 1e-12f) / s2;  // 1/sigma
    }
  }
  __syncthreads();

  const int px = tid & 15;
  const int rg = tid >> 4;        // row group: rows rg*5 .. rg*5+4
  const int p  = p0 + px;
  float acc[5] = {0.f, 0.f, 0.f, 0.f, 0.f};
  for (int c = 0; c < 64; ++c) {
    const float xv = xs[c][px];
    #pragma unroll
    for (int j = 0; j < 5; ++j) acc[j] += Ws[rg * 5 + j][c] * xv;
  }

  const int tile = p >> 5, nt = p & 31;
  const int tt = nt >> 4, gg = (nt >> 2) & 3, ii = nt & 3;
  const int kbase = tile * 512 + nt * 8;       // hi-plane slot (ushorts)
  #pragma unroll
  for (int j = 0; j < 5; ++j) {
    const int r = rg * 5 + j;
    if (r < 8) {
      const float vq = (acc[j] * is_s[0] + bfv[r]) * 0.25f;  // folds /4
      const __hip_bfloat16 h = __float2bfloat16(vq);
      const float hf = __bfloat162float(h);
      const __hip_bfloat16 lo = __float2bfloat16(vq - hf);
      Qp[p * 16 + r]     = *(const ushort*)&h;
      Qp[p * 16 + 8 + r] = *(const ushort*)&lo;
    } else if (r < 16) {
      const int rk = r - 8;
      const float val = acc[j] * is_s[1] + bgv[rk];
      const __hip_bfloat16 h = __float2bfloat16(val);
      const float hf = __bfloat162float(h);
      const __hip_bfloat16 lo = __float2bfloat16(val - hf);
      Kp[kbase + rk]        = *(const ushort*)&h;   // hi plane
      Kp[kbase + 256 + rk]  = *(const ushort*)&lo;  // lo plane (+512 B)
    } else {
      const int rv = r - 16;
      const float val = acc[j] * is_s[2] + bhv[rv];
      const __hip_bfloat16 hv = __float2bfloat16(val);
      const int idx = tile * 2048 +
          ((rv * 32 + gg * 8 + tt * 4 + ii) ^ (((rv >> 1) & 7) << 3));
      Vt2[idx] = *(const ushort*)&hv;
    }
  }
}

// ---------------- Kernel 2: flash attention, counted-vmcnt pipeline ---------
// Grid (144, S). Block = 64 m-rows; 4 waves convoyed by one raw s_barrier per
// tile; 4 LDS buffers, depth-2 prefetch, vmcnt never drained in steady state.
// K plane-split layout (linear); V XOR swizzle matches the fgh writer.
template <int S>
__global__ __launch_bounds__(256) void attn_kernel(
    const ushort* __restrict__ Qp, const ushort* __restrict__ Kp,
    const ushort* __restrict__ Vt2,
    ushort* __restrict__ Om,   // [576 mt][S][1024] bf16 (e = c*16 + m)
    float* __restrict__ Sm) {  // [576 mt][S][32]  f32 (16 mx, 16 ls)
  constexpr int NSEG = NPIX / S;
  constexpr int NT = NSEG / 32;
  __shared__ ushort Vs[4][2048];  // 4 x 4KB
  __shared__ ushort Ks[4][512];   // 4 x 1KB
  const int tid  = threadIdx.x;
  const int w    = tid >> 6;
  const int l    = tid & 63;
  const int mloc = l & 15;
  const int g    = l >> 4;
  const int spl  = blockIdx.y;
  const int mrow = blockIdx.x * 64 + w * 16 + mloc;

  bf16x8 qh = *(const bf16x8*)(Qp + mrow * 16);
  bf16x8 ql = *(const bf16x8*)(Qp + mrow * 16 + 8);
  asm volatile("" : "+v"(qh), "+v"(ql));

  const int n0 = spl * NSEG;
  const char* vsrc = (const char*)Vt2 + ((size_t)(n0 >> 5)) * 4096 + w * 1024 + l * 16;
  const char* ksrc = (const char*)Kp + ((size_t)(n0 >> 5)) * 1024 + w * 256 + l * 4;

  #define STAGE(t_) do {                                                  \
    const int b_ = (t_) & 3;                                              \
    gload_lds16(vsrc + (size_t)(t_) * 4096, (char*)&Vs[b_][0] + w * 1024);\
    gload_lds4 (ksrc + (size_t)(t_) * 1024, (char*)&Ks[b_][0] + w * 256); \
  } while (0)

  STAGE(0);
  STAGE(1);

  const unsigned ks_base = LDS_OFF(&Ks[0][0]);
  const unsigned vs_base = LDS_OFF(&Vs[0][0]);
  const unsigned vswz = (mloc * 64 + g * 16) ^ (((mloc >> 1) & 7) << 4);

  float mx = -INFINITY, ls = 0.f;
  const f32x4 zero = {0.f, 0.f, 0.f, 0.f};
  f32x4 acc0 = zero, acc1 = zero, acc2 = zero, acc3 = zero;

  for (int t = 0; t < NT; ++t) {
    const int b = t & 3;
    if (t + 2 < NT) {
      STAGE(t + 2);
      asm volatile("s_waitcnt vmcnt(4)" ::: "memory");
    } else if (t + 1 < NT) {
      asm volatile("s_waitcnt vmcnt(2)" ::: "memory");
    } else {
      asm volatile("s_waitcnt vmcnt(0)" ::: "memory");
    }
    __builtin_amdgcn_s_barrier();

    // K: hi@0, row16hi@256, lo@512, row16lo@768 (plane-split, additive)
    const unsigned kaddr = ks_base + b * 1024 + mloc * 16;
    const unsigned vaddr = vs_base + b * 4096 + vswz;
    bf16x8 kh0, kl0, kh1, kl1, v0, v1, v2, v3;
    asm volatile("ds_read_b128 %0, %1"            : "=v"(kh0) : "v"(kaddr));
    asm volatile("ds_read_b128 %0, %1 offset:256" : "=v"(kh1) : "v"(kaddr));
    asm volatile("ds_read_b128 %0, %1 offset:512" : "=v"(kl0) : "v"(kaddr));
    asm volatile("ds_read_b128 %0, %1 offset:768" : "=v"(kl1) : "v"(kaddr));
    asm volatile("ds_read_b128 %0, %1"            : "=v"(v0)  : "v"(vaddr));
    asm volatile("ds_read_b128 %0, %1 offset:1024": "=v"(v1)  : "v"(vaddr));
    asm volatile("ds_read_b128 %0, %1 offset:2048": "=v"(v2)  : "v"(vaddr));
    asm volatile("ds_read_b128 %0, %1 offset:3072": "=v"(v3)  : "v"(vaddr));
    asm volatile("s_waitcnt lgkmcnt(0)" ::: "memory");
    __builtin_amdgcn_sched_barrier(0);  // rule #18

    // ---- S^T = K . Q^T ----
    f32x4 s0 = zero, s1 = zero;
    s0 = __builtin_amdgcn_mfma_f32_16x16x32_bf16(kh0, qh, s0, 0, 0, 0);
    s1 = __builtin_amdgcn_mfma_f32_16x16x32_bf16(kh1, qh, s1, 0, 0, 0);
    s0 = __builtin_amdgcn_mfma_f32_16x16x32_bf16(kh0, ql, s0, 0, 0, 0);
    s1 = __builtin_amdgcn_mfma_f32_16x16x32_bf16(kh1, ql, s1, 0, 0, 0);
    s0 = __builtin_amdgcn_mfma_f32_16x16x32_bf16(kl0, qh, s0, 0, 0, 0);
    s1 = __builtin_amdgcn_mfma_f32_16x16x32_bf16(kl1, qh, s1, 0, 0, 0);

    // ---- online softmax: common path has zero cross-lane ops ----
    const float tm = fmaxf(
        fmaxf(fmaxf(s0[0], s0[1]), fmaxf(s0[2], s0[3])),
        fmaxf(fmaxf(s1[0], s1[1]), fmaxf(s1[2], s1[3])));
    if (__any(tm > mx + 8.0f)) {   // rare
      float tr = fmaxf(tm, __shfl_xor(tm, 16));
      tr = fmaxf(tr, __shfl_xor(tr, 32));
      const float mxn = fmaxf(mx, tr);
      const float corr = __expf(mx - mxn);
      ls *= corr;
      const float c0 = __shfl(corr, (g << 2) + 0);
      const float c1 = __shfl(corr, (g << 2) + 1);
      const float c2 = __shfl(corr, (g << 2) + 2);
      const float c3 = __shfl(corr, (g << 2) + 3);
      acc0[0] *= c0; acc0[1] *= c1; acc0[2] *= c2; acc0[3] *= c3;
      acc1[0] *= c0; acc1[1] *= c1; acc1[2] *= c2; acc1[3] *= c3;
      acc2[0] *= c0; acc2[1] *= c1; acc2[2] *= c2; acc2[3] *= c3;
      acc3[0] *= c0; acc3[1] *= c1; acc3[2] *= c2; acc3[3] *= c3;
      mx = mxn;
    }
    float pj[8];
    pj[0] = __expf(s0[0] - mx); pj[1] = __expf(s0[1] - mx);
    pj[2] = __expf(s0[2] - mx); pj[3] = __expf(s0[3] - mx);
    pj[4] = __expf(s1[0] - mx); pj[5] = __expf(s1[1] - mx);
    pj[6] = __expf(s1[2] - mx); pj[7] = __expf(s1[3] - mx);
    ls += ((pj[0] + pj[1]) + (pj[2] + pj[3])) + ((pj[4] + pj[5]) + (pj[6] + pj[7]));

    union { unsigned int u[4]; bf16x8 v; } pu;
    #pragma unroll
    for (int jj = 0; jj < 4; ++jj) {
      unsigned int r;
      asm("v_cvt_pk_bf16_f32 %0, %1, %2" : "=v"(r) : "v"(pj[2 * jj]), "v"(pj[2 * jj + 1]));
      pu.u[jj] = r;
    }
    // ---- PV ----
    acc0 = __builtin_amdgcn_mfma_f32_16x16x32_bf16(pu.v, v0, acc0, 0, 0, 0);
    acc1 = __builtin_amdgcn_mfma_f32_16x16x32_bf16(pu.v, v1, acc1, 0, 0, 0);
    acc2 = __builtin_amdgcn_mfma_f32_16x16x32_bf16(pu.v, v2, acc2, 0, 0, 0);
    acc3 = __builtin_amdgcn_mfma_f32_16x16x32_bf16(pu.v, v3, acc3, 0, 0, 0);
  }
  #undef STAGE

  ls += __shfl_xor(ls, 16);
  ls += __shfl_xor(ls, 32);

  const size_t mt = (size_t)blockIdx.x * 4 + w;
  ushort* Ob = Om + (mt * S + spl) * 1024;
  float*  Sb = Sm + (mt * S + spl) * 32;
  #pragma unroll
  for (int ct = 0; ct < 4; ++ct) {
    const f32x4 a = (ct == 0) ? acc0 : (ct == 1) ? acc1 : (ct == 2) ? acc2 : acc3;
    unsigned int r0, r1;
    asm("v_cvt_pk_bf16_f32 %0, %1, %2" : "=v"(r0) : "v"(a[0]), "v"(a[1]));
    asm("v_cvt_pk_bf16_f32 %0, %1, %2" : "=v"(r1) : "v"(a[2]), "v"(a[3]));
    u32x2 pk; pk[0] = r0; pk[1] = r1;
    *(u32x2*)(Ob + (ct * 16 + mloc) * 16 + 4 * g) = pk;  // e = c*16 + (4g+i)
  }
  if (l < 16) { Sb[l] = mx; Sb[16 + l] = ls; }
}

// ---------------- Kernel 3: combine split partials ---------------------------
template <int S>
__global__ __launch_bounds__(256) void combine_kernel(
    const ushort* __restrict__ Om, const float* __restrict__ Sm,
    const float* __restrict__ x, const float* __restrict__ gammap,
    float* __restrict__ out) {
  const int mt = blockIdx.x;
  const int m0 = mt * 16;
  const float gamma = gammap[0];
  const float* Sb = Sm + (size_t)mt * S * 32;
  const ushort* Ob = Om + (size_t)mt * S * 1024;
  for (int e = threadIdx.x; e < 1024; e += 256) {
    const int m = e & 15, c = e >> 4;
    float M = -INFINITY;
    #pragma unroll
    for (int s = 0; s < S; ++s) M = fmaxf(M, Sb[s * 32 + m]);
    float L = 0.f, val = 0.f;
    #pragma unroll
    for (int s = 0; s < S; ++s) {
      const float wgt = __expf(Sb[s * 32 + m] - M);
      L += Sb[s * 32 + 16 + m] * wgt;
      union { unsigned int i; float f; } cv;
      cv.i = ((unsigned int)Ob[s * 1024 + e]) << 16;
      val += cv.f * wgt;
    }
    const int idx = c * NPIX + m0 + m;
    out[idx] = gamma * (val / L) + x[idx];
  }
}

// ---------------- launcher ---------------------------------------------------
extern "C" void kernel_launch(void* const* d_in, const int* in_sizes, int n_in,
                              void* d_out, int out_size, void* d_ws, size_t ws_size,
                              hipStream_t stream) {
  const float* x     = (const float*)d_in[0];
  const float* Wf    = (const float*)d_in[1];
  const float* bf    = (const float*)d_in[2];
  const float* Wg    = (const float*)d_in[3];
  const float* bg    = (const float*)d_in[4];
  const float* Wh    = (const float*)d_in[5];
  const float* bh    = (const float*)d_in[6];
  const float* gamma = (const float*)d_in[7];
  const float* uf    = (const float*)d_in[8];
  const float* ug    = (const float*)d_in[9];
  const float* uh    = (const float*)d_in[10];
  float* out = (float*)d_out;

  char* ws = (char*)d_ws;
  ushort* Qp  = (ushort*)(ws + 256);                                 // 294912 B
  ushort* Kp  = (ushort*)(ws + 256 + NPIX * 16 * 2);                 // 294912 B
  ushort* Vt2 = (ushort*)(ws + 256 + 2 * NPIX * 16 * 2);             // 1179648 B
  const size_t off = 256 + (size_t)2 * NPIX * 16 * 2 + (size_t)NPIX * 64 * 2;
  ushort* Om = (ushort*)(ws + off);
  const size_t need16 = off + (size_t)MTILES * 16 * 1024 * 2 + (size_t)MTILES * 16 * 32 * 4;

  fgh_kernel<<<NPIX / 16, 256, 0, stream>>>(x, Wf, bf, Wg, bg, Wh, bh,
                                            uf, ug, uh, Qp, Kp, Vt2);
  if (ws_size >= need16) {
    float* Sm = (float*)(ws + off + (size_t)MTILES * 16 * 1024 * 2);
    attn_kernel<16><<<dim3(NPIX / 64, 16), 256, 0, stream>>>(Qp, Kp, Vt2, Om, Sm);
    combine_kernel<16><<<MTILES, 256, 0, stream>>>(Om, Sm, x, gamma, out);
  } else {
    float* Sm = (float*)(ws + off + (size_t)MTILES * 8 * 1024 * 2);
    attn_kernel<8><<<dim3(NPIX / 64, 8), 256, 0, stream>>>(Qp, Kp, Vt2, Om, Sm);
    combine_kernel<8><<<MTILES, 256, 0, stream>>>(Om, Sm, x, gamma, out);
  }
}

// Round 9
// 77.601 us; speedup vs baseline: 1.1701x; 1.1701x over previous
//
#include <hip/hip_runtime.h>
#include <hip/hip_bf16.h>

#define NPIX 9216
#define MTILES (NPIX / 16)    // 576

typedef __attribute__((ext_vector_type(4))) float f32x4;
typedef __attribute__((ext_vector_type(8))) short bf16x8;
typedef __attribute__((ext_vector_type(2))) unsigned int u32x2;

__device__ __forceinline__ void gload_lds16(const void* g, void* l) {
  __builtin_amdgcn_global_load_lds(
      (const __attribute__((address_space(1))) unsigned int*)g,
      (__attribute__((address_space(3))) unsigned int*)l, 16, 0, 0);
}
__device__ __forceinline__ void gload_lds4(const void* g, void* l) {
  __builtin_amdgcn_global_load_lds(
      (const __attribute__((address_space(1))) unsigned int*)g,
      (__attribute__((address_space(3))) unsigned int*)l, 4, 0, 0);
}
#define LDS_OFF(p) ((unsigned)(unsigned long long)(const __attribute__((address_space(3))) char*)(const char*)(p))

// ---------------- Kernel 0: spectral sigmas -> pre-scaled weights ------------
// 1 block, 256 threads. Waves 0/1/2 compute sigma for Wf/Wg/Wh in parallel
// (3 concurrent dependent chains). Then all threads write
//   Wsc[80][64]: rows 0-7  = Wf * (0.25/sig_f)   (0.25 folds K-broadcast /4)
//                rows 8-15 = Wg * (1/sig_g)
//                rows 16-79= Wh * (1/sig_h)
//   bsc[80]    : bf*0.25, bg, bh
__global__ __launch_bounds__(256) void spectral_kernel(
    const float* __restrict__ Wf, const float* __restrict__ bfv,
    const float* __restrict__ Wg, const float* __restrict__ bgv,
    const float* __restrict__ Wh, const float* __restrict__ bhv,
    const float* __restrict__ uf, const float* __restrict__ ug,
    const float* __restrict__ uh,
    float* __restrict__ Wsc, float* __restrict__ bsc) {
  __shared__ float vsh3[3][64];
  __shared__ float is_s[3];
  const int tid = threadIdx.x;
  const int wv = tid >> 6, t = tid & 63;
  if (wv < 3) {
    const float* W = (wv == 0) ? Wf : (wv == 1) ? Wg : Wh;
    const float* u = (wv == 0) ? uf : (wv == 1) ? ug : uh;
    const int O = (wv == 2) ? 64 : 8;
    float v = 0.f;
    for (int o = 0; o < O; ++o) v += W[o * 64 + t] * u[o];
    float s = v * v;
    for (int off = 32; off; off >>= 1) s += __shfl_xor(s, off);
    vsh3[wv][t] = v / (sqrtf(s) + 1e-12f);   // wave-lockstep within wave
    float wvv = 0.f;
    if (t < O) { for (int c = 0; c < 64; ++c) wvv += W[t * 64 + c] * vsh3[wv][c]; }
    float s2 = (t < O) ? wvv * wvv : 0.f;
    for (int off = 32; off; off >>= 1) s2 += __shfl_xor(s2, off);
    const float nw = sqrtf(s2);
    if (t == 0) is_s[wv] = (nw + 1e-12f) / s2;  // 1/sigma
  }
  __syncthreads();
  const float sf = is_s[0] * 0.25f, sg = is_s[1], sh = is_s[2];
  for (int e = tid; e < 5120; e += 256) {
    const int r = e >> 6, c = e & 63;
    float val;
    if (r < 8)       val = Wf[r * 64 + c] * sf;
    else if (r < 16) val = Wg[(r - 8) * 64 + c] * sg;
    else             val = Wh[(r - 16) * 64 + c] * sh;
    Wsc[e] = val;
  }
  if (tid < 80) {
    bsc[tid] = (tid < 8) ? bfv[tid] * 0.25f
             : (tid < 16) ? bgv[tid - 8] : bhv[tid - 16];
  }
}

// ---------------- Kernel 1: f,g,h projections (uniform-W GEMV) ---------------
// Grid (144, 5): block = 64 pixels x 16 rows (rows by*16..+15).
// Thread: px = tid&63 (coalesced), 4 rows (wave-uniform via readfirstlane ->
// Wsc/bsc fetched through s_load, FMAs are v_fmac v,s,v; zero LDS).
// Output layouts identical to R7 (verified):
//   Qp  [NPIX][16] hi/lo;  Kp plane-split per 1KB tile;  Vt2 XOR-swizzled.
__global__ __launch_bounds__(256) void fgh_kernel(
    const float* __restrict__ x,
    const float* __restrict__ Wsc, const float* __restrict__ bsc,
    ushort* __restrict__ Qp, ushort* __restrict__ Kp, ushort* __restrict__ Vt2) {
  const int tid = threadIdx.x;
  const int px = tid & 63;
  const int rw = __builtin_amdgcn_readfirstlane(tid >> 6);  // wave row-group
  const int r0 = blockIdx.y * 16 + rw * 4;                  // 4 rows r0..r0+3
  const int p  = blockIdx.x * 64 + px;

  float xv[64];
  #pragma unroll
  for (int c = 0; c < 64; ++c) xv[c] = x[c * NPIX + p];

  float acc0 = 0.f, acc1 = 0.f, acc2 = 0.f, acc3 = 0.f;
  const float* w0 = Wsc + (r0 + 0) * 64;
  const float* w1 = Wsc + (r0 + 1) * 64;
  const float* w2 = Wsc + (r0 + 2) * 64;
  const float* w3 = Wsc + (r0 + 3) * 64;
  #pragma unroll
  for (int c = 0; c < 64; ++c) {
    const float xc = xv[c];
    acc0 += w0[c] * xc; acc1 += w1[c] * xc;
    acc2 += w2[c] * xc; acc3 += w3[c] * xc;
  }

  const int tile = p >> 5, nt = p & 31;
  const int tt = nt >> 4, gg = (nt >> 2) & 3, ii = nt & 3;
  const int kbase = tile * 512 + nt * 8;       // K hi-plane slot (ushorts)
  float accs[4] = {acc0, acc1, acc2, acc3};
  #pragma unroll
  for (int j = 0; j < 4; ++j) {
    const int r = r0 + j;
    const float val = accs[j] + bsc[r];
    if (r < 8) {
      const __hip_bfloat16 h = __float2bfloat16(val);
      const float hf = __bfloat162float(h);
      const __hip_bfloat16 lo = __float2bfloat16(val - hf);
      Qp[p * 16 + r]     = *(const ushort*)&h;
      Qp[p * 16 + 8 + r] = *(const ushort*)&lo;
    } else if (r < 16) {
      const int rk = r - 8;
      const __hip_bfloat16 h = __float2bfloat16(val);
      const float hf = __bfloat162float(h);
      const __hip_bfloat16 lo = __float2bfloat16(val - hf);
      Kp[kbase + rk]       = *(const ushort*)&h;   // hi plane
      Kp[kbase + 256 + rk] = *(const ushort*)&lo;  // lo plane (+512 B)
    } else {
      const int rv = r - 16;
      const __hip_bfloat16 hv = __float2bfloat16(val);
      const int idx = tile * 2048 +
          ((rv * 32 + gg * 8 + tt * 4 + ii) ^ (((rv >> 1) & 7) << 3));
      Vt2[idx] = *(const ushort*)&hv;
    }
  }
}

// ---------------- Kernel 2: flash attention, counted-vmcnt pipeline ---------
// (identical to R7 — verified)
template <int S>
__global__ __launch_bounds__(256) void attn_kernel(
    const ushort* __restrict__ Qp, const ushort* __restrict__ Kp,
    const ushort* __restrict__ Vt2,
    ushort* __restrict__ Om,   // [576 mt][S][1024] bf16 (e = c*16 + m)
    float* __restrict__ Sm) {  // [576 mt][S][32]  f32 (16 mx, 16 ls)
  constexpr int NSEG = NPIX / S;
  constexpr int NT = NSEG / 32;
  __shared__ ushort Vs[4][2048];  // 4 x 4KB
  __shared__ ushort Ks[4][512];   // 4 x 1KB
  const int tid  = threadIdx.x;
  const int w    = tid >> 6;
  const int l    = tid & 63;
  const int mloc = l & 15;
  const int g    = l >> 4;
  const int spl  = blockIdx.y;
  const int mrow = blockIdx.x * 64 + w * 16 + mloc;

  bf16x8 qh = *(const bf16x8*)(Qp + mrow * 16);
  bf16x8 ql = *(const bf16x8*)(Qp + mrow * 16 + 8);
  asm volatile("" : "+v"(qh), "+v"(ql));

  const int n0 = spl * NSEG;
  const char* vsrc = (const char*)Vt2 + ((size_t)(n0 >> 5)) * 4096 + w * 1024 + l * 16;
  const char* ksrc = (const char*)Kp + ((size_t)(n0 >> 5)) * 1024 + w * 256 + l * 4;

  #define STAGE(t_) do {                                                  \
    const int b_ = (t_) & 3;                                              \
    gload_lds16(vsrc + (size_t)(t_) * 4096, (char*)&Vs[b_][0] + w * 1024);\
    gload_lds4 (ksrc + (size_t)(t_) * 1024, (char*)&Ks[b_][0] + w * 256); \
  } while (0)

  STAGE(0);
  STAGE(1);

  const unsigned ks_base = LDS_OFF(&Ks[0][0]);
  const unsigned vs_base = LDS_OFF(&Vs[0][0]);
  const unsigned vswz = (mloc * 64 + g * 16) ^ (((mloc >> 1) & 7) << 4);

  float mx = -INFINITY, ls = 0.f;
  const f32x4 zero = {0.f, 0.f, 0.f, 0.f};
  f32x4 acc0 = zero, acc1 = zero, acc2 = zero, acc3 = zero;

  for (int t = 0; t < NT; ++t) {
    const int b = t & 3;
    if (t + 2 < NT) {
      STAGE(t + 2);
      asm volatile("s_waitcnt vmcnt(4)" ::: "memory");
    } else if (t + 1 < NT) {
      asm volatile("s_waitcnt vmcnt(2)" ::: "memory");
    } else {
      asm volatile("s_waitcnt vmcnt(0)" ::: "memory");
    }
    __builtin_amdgcn_s_barrier();

    // K: hi@0, row16hi@256, lo@512, row16lo@768 (plane-split, additive)
    const unsigned kaddr = ks_base + b * 1024 + mloc * 16;
    const unsigned vaddr = vs_base + b * 4096 + vswz;
    bf16x8 kh0, kl0, kh1, kl1, v0, v1, v2, v3;
    asm volatile("ds_read_b128 %0, %1"            : "=v"(kh0) : "v"(kaddr));
    asm volatile("ds_read_b128 %0, %1 offset:256" : "=v"(kh1) : "v"(kaddr));
    asm volatile("ds_read_b128 %0, %1 offset:512" : "=v"(kl0) : "v"(kaddr));
    asm volatile("ds_read_b128 %0, %1 offset:768" : "=v"(kl1) : "v"(kaddr));
    asm volatile("ds_read_b128 %0, %1"            : "=v"(v0)  : "v"(vaddr));
    asm volatile("ds_read_b128 %0, %1 offset:1024": "=v"(v1)  : "v"(vaddr));
    asm volatile("ds_read_b128 %0, %1 offset:2048": "=v"(v2)  : "v"(vaddr));
    asm volatile("ds_read_b128 %0, %1 offset:3072": "=v"(v3)  : "v"(vaddr));
    asm volatile("s_waitcnt lgkmcnt(0)" ::: "memory");
    __builtin_amdgcn_sched_barrier(0);  // rule #18

    // ---- S^T = K . Q^T ----
    f32x4 s0 = zero, s1 = zero;
    s0 = __builtin_amdgcn_mfma_f32_16x16x32_bf16(kh0, qh, s0, 0, 0, 0);
    s1 = __builtin_amdgcn_mfma_f32_16x16x32_bf16(kh1, qh, s1, 0, 0, 0);
    s0 = __builtin_amdgcn_mfma_f32_16x16x32_bf16(kh0, ql, s0, 0, 0, 0);
    s1 = __builtin_amdgcn_mfma_f32_16x16x32_bf16(kh1, ql, s1, 0, 0, 0);
    s0 = __builtin_amdgcn_mfma_f32_16x16x32_bf16(kl0, qh, s0, 0, 0, 0);
    s1 = __builtin_amdgcn_mfma_f32_16x16x32_bf16(kl1, qh, s1, 0, 0, 0);

    // ---- online softmax: common path has zero cross-lane ops ----
    const float tm = fmaxf(
        fmaxf(fmaxf(s0[0], s0[1]), fmaxf(s0[2], s0[3])),
        fmaxf(fmaxf(s1[0], s1[1]), fmaxf(s1[2], s1[3])));
    if (__any(tm > mx + 8.0f)) {   // rare
      float tr = fmaxf(tm, __shfl_xor(tm, 16));
      tr = fmaxf(tr, __shfl_xor(tr, 32));
      const float mxn = fmaxf(mx, tr);
      const float corr = __expf(mx - mxn);
      ls *= corr;
      const float c0 = __shfl(corr, (g << 2) + 0);
      const float c1 = __shfl(corr, (g << 2) + 1);
      const float c2 = __shfl(corr, (g << 2) + 2);
      const float c3 = __shfl(corr, (g << 2) + 3);
      acc0[0] *= c0; acc0[1] *= c1; acc0[2] *= c2; acc0[3] *= c3;
      acc1[0] *= c0; acc1[1] *= c1; acc1[2] *= c2; acc1[3] *= c3;
      acc2[0] *= c0; acc2[1] *= c1; acc2[2] *= c2; acc2[3] *= c3;
      acc3[0] *= c0; acc3[1] *= c1; acc3[2] *= c2; acc3[3] *= c3;
      mx = mxn;
    }
    float pj[8];
    pj[0] = __expf(s0[0] - mx); pj[1] = __expf(s0[1] - mx);
    pj[2] = __expf(s0[2] - mx); pj[3] = __expf(s0[3] - mx);
    pj[4] = __expf(s1[0] - mx); pj[5] = __expf(s1[1] - mx);
    pj[6] = __expf(s1[2] - mx); pj[7] = __expf(s1[3] - mx);
    ls += ((pj[0] + pj[1]) + (pj[2] + pj[3])) + ((pj[4] + pj[5]) + (pj[6] + pj[7]));

    union { unsigned int u[4]; bf16x8 v; } pu;
    #pragma unroll
    for (int jj = 0; jj < 4; ++jj) {
      unsigned int r;
      asm("v_cvt_pk_bf16_f32 %0, %1, %2" : "=v"(r) : "v"(pj[2 * jj]), "v"(pj[2 * jj + 1]));
      pu.u[jj] = r;
    }
    // ---- PV ----
    acc0 = __builtin_amdgcn_mfma_f32_16x16x32_bf16(pu.v, v0, acc0, 0, 0, 0);
    acc1 = __builtin_amdgcn_mfma_f32_16x16x32_bf16(pu.v, v1, acc1, 0, 0, 0);
    acc2 = __builtin_amdgcn_mfma_f32_16x16x32_bf16(pu.v, v2, acc2, 0, 0, 0);
    acc3 = __builtin_amdgcn_mfma_f32_16x16x32_bf16(pu.v, v3, acc3, 0, 0, 0);
  }
  #undef STAGE

  ls += __shfl_xor(ls, 16);
  ls += __shfl_xor(ls, 32);

  const size_t mt = (size_t)blockIdx.x * 4 + w;
  ushort* Ob = Om + (mt * S + spl) * 1024;
  float*  Sb = Sm + (mt * S + spl) * 32;
  #pragma unroll
  for (int ct = 0; ct < 4; ++ct) {
    const f32x4 a = (ct == 0) ? acc0 : (ct == 1) ? acc1 : (ct == 2) ? acc2 : acc3;
    unsigned int r0, r1;
    asm("v_cvt_pk_bf16_f32 %0, %1, %2" : "=v"(r0) : "v"(a[0]), "v"(a[1]));
    asm("v_cvt_pk_bf16_f32 %0, %1, %2" : "=v"(r1) : "v"(a[2]), "v"(a[3]));
    u32x2 pk; pk[0] = r0; pk[1] = r1;
    *(u32x2*)(Ob + (ct * 16 + mloc) * 16 + 4 * g) = pk;  // e = c*16 + (4g+i)
  }
  if (l < 16) { Sb[l] = mx; Sb[16 + l] = ls; }
}

// ---------------- Kernel 3: combine split partials ---------------------------
template <int S>
__global__ __launch_bounds__(256) void combine_kernel(
    const ushort* __restrict__ Om, const float* __restrict__ Sm,
    const float* __restrict__ x, const float* __restrict__ gammap,
    float* __restrict__ out) {
  const int mt = blockIdx.x;
  const int m0 = mt * 16;
  const float gamma = gammap[0];
  const float* Sb = Sm + (size_t)mt * S * 32;
  const ushort* Ob = Om + (size_t)mt * S * 1024;
  for (int e = threadIdx.x; e < 1024; e += 256) {
    const int m = e & 15, c = e >> 4;
    float M = -INFINITY;
    #pragma unroll
    for (int s = 0; s < S; ++s) M = fmaxf(M, Sb[s * 32 + m]);
    float L = 0.f, val = 0.f;
    #pragma unroll
    for (int s = 0; s < S; ++s) {
      const float wgt = __expf(Sb[s * 32 + m] - M);
      L += Sb[s * 32 + 16 + m] * wgt;
      union { unsigned int i; float f; } cv;
      cv.i = ((unsigned int)Ob[s * 1024 + e]) << 16;
      val += cv.f * wgt;
    }
    const int idx = c * NPIX + m0 + m;
    out[idx] = gamma * (val / L) + x[idx];
  }
}

// ---------------- launcher ---------------------------------------------------
extern "C" void kernel_launch(void* const* d_in, const int* in_sizes, int n_in,
                              void* d_out, int out_size, void* d_ws, size_t ws_size,
                              hipStream_t stream) {
  const float* x     = (const float*)d_in[0];
  const float* Wf    = (const float*)d_in[1];
  const float* bf    = (const float*)d_in[2];
  const float* Wg    = (const float*)d_in[3];
  const float* bg    = (const float*)d_in[4];
  const float* Wh    = (const float*)d_in[5];
  const float* bh    = (const float*)d_in[6];
  const float* gamma = (const float*)d_in[7];
  const float* uf    = (const float*)d_in[8];
  const float* ug    = (const float*)d_in[9];
  const float* uh    = (const float*)d_in[10];
  float* out = (float*)d_out;

  char* ws = (char*)d_ws;
  float*  Wsc = (float*)(ws);                                        // 20480 B
  float*  bsc = (float*)(ws + 20480);                                // 320 B
  ushort* Qp  = (ushort*)(ws + 21504);                               // 294912 B
  ushort* Kp  = (ushort*)(ws + 21504 + NPIX * 16 * 2);               // 294912 B
  ushort* Vt2 = (ushort*)(ws + 21504 + 2 * NPIX * 16 * 2);           // 1179648 B
  const size_t off = 21504 + (size_t)2 * NPIX * 16 * 2 + (size_t)NPIX * 64 * 2;
  ushort* Om = (ushort*)(ws + off);
  const size_t need16 = off + (size_t)MTILES * 16 * 1024 * 2 + (size_t)MTILES * 16 * 32 * 4;

  spectral_kernel<<<1, 256, 0, stream>>>(Wf, bf, Wg, bg, Wh, bh, uf, ug, uh, Wsc, bsc);
  fgh_kernel<<<dim3(NPIX / 64, 5), 256, 0, stream>>>(x, Wsc, bsc, Qp, Kp, Vt2);
  if (ws_size >= need16) {
    float* Sm = (float*)(ws + off + (size_t)MTILES * 16 * 1024 * 2);
    attn_kernel<16><<<dim3(NPIX / 64, 16), 256, 0, stream>>>(Qp, Kp, Vt2, Om, Sm);
    combine_kernel<16><<<MTILES, 256, 0, stream>>>(Om, Sm, x, gamma, out);
  } else {
    float* Sm = (float*)(ws + off + (size_t)MTILES * 8 * 1024 * 2);
    attn_kernel<8><<<dim3(NPIX / 64, 8), 256, 0, stream>>>(Qp, Kp, Vt2, Om, Sm);
    combine_kernel<8><<<MTILES, 256, 0, stream>>>(Om, Sm, x, gamma, out);
  }
}